// Round 6
// baseline (243.673 us; speedup 1.0000x reference)
//
#include <hip/hip_runtime.h>
#include <math.h>

// Problem constants (ProbAttention: B=4, L=4096, H=8, D=64, S=U=ceil(ln L)=9)
#define B_ 4
#define L_ 4096
#define H_ 8
#define D_ 64
#define S_ 9
#define U_ 9
#define VC_ 64   // vmean stage-1 chunks per batch
#define NC_ 32   // scores chunks per (b,h)  (chunk = 128 keys)
#define CC_ 16   // ctx    chunks per (b,h)  (chunk = 256 keys)
#define TKC_ 8   // topk stage-1 chunks per (b,h)

#define MBLK_ 18432                 // kernel_M blocks: 32 bh * 576 (64 groups each)
#define FILLBLK_ 8192               // fill blocks

__device__ __forceinline__ float dot4(const float4& a, const float4& b) {
    return a.x * b.x + a.y * b.y + a.z * b.z + a.w * b.w;
}

// ---------------------------------------------------------------------------
// K1: fused raw-dot gather (blocks < MBLK_) + vmean1 (blocks >= MBLK_).
// Gather: one (l,s) dot per 4-lane group, no LDS, no barrier — max TLP
// (73728 waves). dots[bh][s][l] written s-major for coalesced topk1 reads.
// M finalize (max - mean) happens in topk1.
// ---------------------------------------------------------------------------
__global__ void kernel_Mv(const float* __restrict__ Q, const float* __restrict__ K,
                          const int* __restrict__ idx, float* __restrict__ dots,
                          const float* __restrict__ V, float* __restrict__ vpart) {
    if (blockIdx.x >= MBLK_) {
        // ---- vmean1: coalesced float4 partial sums over (l,h,d) ----
        int blk = blockIdx.x - MBLK_;
        int c = blk & (VC_ - 1), b = blk >> 6;
        int col = threadIdx.x & 127;
        int lp  = threadIdx.x >> 7;
        const int CHUNK = L_ / VC_;
        const float4* base = (const float4*)(V + (size_t)b * L_ * H_ * D_);
        float4 acc = make_float4(0.f, 0.f, 0.f, 0.f);
        for (int l = c * CHUNK + lp; l < (c + 1) * CHUNK; l += 2) {
            float4 v = base[(size_t)l * 128 + col];
            acc.x += v.x; acc.y += v.y; acc.z += v.z; acc.w += v.w;
        }
        __shared__ float4 red[256];
        red[threadIdx.x] = acc;
        __syncthreads();
        if (lp == 0) {
            float4 o = red[threadIdx.x + 128];
            acc.x += o.x; acc.y += o.y; acc.z += o.z; acc.w += o.w;
            ((float4*)vpart)[(size_t)blk * 128 + col] = acc;
        }
        return;
    }
    // ---- gather part: XCD-swizzled (bh % 8 == XCD) ----
    int n = blockIdx.x;
    int x = n & 7, m = n >> 3;          // m in [0, 2304)
    int bhi = m / 576, blk = m - bhi * 576;
    int bh = bhi * 8 + x;
    int h = bh & (H_ - 1), b = bh >> 3;
    int t = threadIdx.x;
    int j = t & 3;                      // lane within 4-lane dot group
    int G = blk * 64 + (t >> 2);        // group id in [0, 36864)
    int s = G >> 12;                    // sample 0..8
    int l = G & (L_ - 1);

    int ki = idx[l * S_ + s];
    const float4* qb = (const float4*)(Q + (size_t)((b * L_ + l) * H_ + h) * D_);
    const float4* kb = (const float4*)(K + (size_t)((b * L_ + ki) * H_ + h) * D_);

    float acc = 0.0f;
#pragma unroll
    for (int c = 0; c < 4; ++c) acc += dot4(qb[j + 4 * c], kb[j + 4 * c]);
    acc += __shfl_xor(acc, 1);
    acc += __shfl_xor(acc, 2);
    if (j == 0) dots[((size_t)bh * S_ + s) * L_ + l] = acc;
}

// ---------------------------------------------------------------------------
// Top-k stage 1 (value desc, index asc) — matches jax.lax.top_k.
// Computes M = max_s(dot) - sum_s(dot)/L on the fly from s-major dots.
// ---------------------------------------------------------------------------
#define CSWAP(a, b)                                                          \
    if (v[b] > v[a] || (v[b] == v[a] && id[b] < id[a])) {                    \
        float tv = v[a]; v[a] = v[b]; v[b] = tv;                             \
        int ti = id[a]; id[a] = id[b]; id[b] = ti;                           \
    }

__global__ void kernel_topk1(const float* __restrict__ dots,
                             float* __restrict__ cand_v, int* __restrict__ cand_i) {
    int bh = blockIdx.x >> 3;
    int chunk = blockIdx.x & (TKC_ - 1);
    int lane = threadIdx.x;
    const float* db = dots + (size_t)bh * S_ * L_;

    float v[8]; int id[8];
#pragma unroll
    for (int c = 0; c < 8; ++c) {
        int gi = chunk * 512 + lane + 64 * c;
        float mx = -INFINITY, sm = 0.0f;
#pragma unroll
        for (int s = 0; s < S_; ++s) {
            float d = db[(size_t)s * L_ + gi];
            mx = fmaxf(mx, d); sm += d;
        }
        v[c] = mx - sm * (1.0f / (float)L_);
        id[c] = gi;
    }
    CSWAP(0,1) CSWAP(2,3) CSWAP(4,5) CSWAP(6,7)
    CSWAP(0,2) CSWAP(1,3) CSWAP(4,6) CSWAP(5,7)
    CSWAP(1,2) CSWAP(5,6)
    CSWAP(0,4) CSWAP(1,5) CSWAP(2,6) CSWAP(3,7)
    CSWAP(2,4) CSWAP(3,5)
    CSWAP(1,2) CSWAP(3,4) CSWAP(5,6)

    float* cv = cand_v + (size_t)blockIdx.x * U_;
    int*   ci = cand_i + (size_t)blockIdx.x * U_;
#pragma unroll
    for (int r = 0; r < U_; ++r) {
        float bv = v[0]; int bi = id[0];
#pragma unroll
        for (int off = 1; off < 64; off <<= 1) {
            float ov = __shfl_xor(bv, off);
            int   oi = __shfl_xor(bi, off);
            if (ov > bv || (ov == bv && oi < bi)) { bv = ov; bi = oi; }
        }
        if (lane == 0) { cv[r] = bv; ci[r] = bi; }
        if (id[0] == bi) {
#pragma unroll
            for (int c = 0; c < 7; ++c) { v[c] = v[c+1]; id[c] = id[c+1]; }
            v[7] = -INFINITY; id[7] = 0x7fffffff;
        }
    }
}

// ---------------------------------------------------------------------------
// K3: fused topk2 (blocks 0..31) + vmean2 (blocks 32..63). 64 threads.
// ---------------------------------------------------------------------------
__global__ void kernel_small(const float* __restrict__ cand_v, const int* __restrict__ cand_i,
                             int* __restrict__ Mtop, const float* __restrict__ vpart,
                             float* __restrict__ vmean) {
    if (blockIdx.x >= 32) {
        int bh = blockIdx.x - 32;
        int h = bh & (H_ - 1), b = bh >> 3;
        int d = threadIdx.x;
        float s = 0.0f;
        for (int c = 0; c < VC_; ++c)
            s += vpart[(size_t)(b * VC_ + c) * (H_ * D_) + h * D_ + d];
        vmean[bh * D_ + d] = s * (1.0f / (float)L_);
        return;
    }
    int bh = blockIdx.x;
    int lane = threadIdx.x;
    const float* cv = cand_v + (size_t)bh * (TKC_ * U_);
    const int*   ci = cand_i + (size_t)bh * (TKC_ * U_);

    float v[2]; int id[2];
    v[0] = cv[lane]; id[0] = ci[lane];
    if (lane < TKC_ * U_ - 64) { v[1] = cv[64 + lane]; id[1] = ci[64 + lane]; }
    else { v[1] = -INFINITY; id[1] = 0x7fffffff; }
    CSWAP(0,1)

#pragma unroll
    for (int r = 0; r < U_; ++r) {
        float bv = v[0]; int bi = id[0];
#pragma unroll
        for (int off = 1; off < 64; off <<= 1) {
            float ov = __shfl_xor(bv, off);
            int   oi = __shfl_xor(bi, off);
            if (ov > bv || (ov == bv && oi < bi)) { bv = ov; bi = oi; }
        }
        if (lane == 0) Mtop[bh * U_ + r] = bi;
        if (id[0] == bi) { v[0] = v[1]; id[0] = id[1]; v[1] = -INFINITY; id[1] = 0x7fffffff; }
    }
}

// ---------------------------------------------------------------------------
// K4: fused fill (blocks < FILLBLK_: vmean broadcast, EXACT 0.0 at top-l
// rows so ctxf can atomicAdd) + scores_raw (blocks >= FILLBLK_).
// ---------------------------------------------------------------------------
__global__ void kernel_fill_scores(float* __restrict__ out, const float* __restrict__ vmean,
                                   const float* __restrict__ Q, const float* __restrict__ K,
                                   const int* __restrict__ Mtop, float* __restrict__ raw) {
    if (blockIdx.x < FILLBLK_) {
        int i = blockIdx.x * 256 + threadIdx.x;
        int d4 = i & 15;
        int h  = (i >> 4) & (H_ - 1);
        int l  = (i >> 7) & (L_ - 1);
        int b  = i >> 19;
        int bh = b * H_ + h;
        bool top = false;
#pragma unroll
        for (int u = 0; u < U_; ++u) top |= (Mtop[bh * U_ + u] == l);
        float4 w = top ? make_float4(0.f, 0.f, 0.f, 0.f)
                       : ((const float4*)vmean)[bh * 16 + d4];
        ((float4*)out)[i] = w;
        return;
    }
    int n = blockIdx.x - FILLBLK_;
    int x = n & 7, m = n >> 3;
    int chunk = m & (NC_ - 1);
    int bh = (m >> 5) * 8 + x;
    int h = bh & (H_ - 1), b = bh >> 3;
    int k0 = chunk * (L_ / NC_);     // 128 keys per block

    __shared__ float qs[U_][D_];
    int t = threadIdx.x;
    if (t < 144) {                   // 9 rows * 16 float4
        int u = t / 16, c = t & 15;
        int l = Mtop[bh * U_ + u];
        ((float4*)qs[u])[c] =
            ((const float4*)(Q + (size_t)((b * L_ + l) * H_ + h) * D_))[c];
    }
    __syncthreads();

    int j = t & 3, g = t >> 2;
#pragma unroll
    for (int kk = 0; kk < 2; ++kk) {
        int k = k0 + g + 64 * kk;
        const float4* kb = (const float4*)(K + (size_t)((b * L_ + k) * H_ + h) * D_);
        float4 kv[4];
#pragma unroll
        for (int c = 0; c < 4; ++c) kv[c] = kb[j + 4 * c];
#pragma unroll
        for (int u = 0; u < U_; ++u) {
            float acc = 0.0f;
#pragma unroll
            for (int c = 0; c < 4; ++c)
                acc += dot4(((const float4*)qs[u])[j + 4 * c], kv[c]);
            acc += __shfl_xor(acc, 1);
            acc += __shfl_xor(acc, 2);
            if (j == 0) raw[((size_t)bh * U_ + u) * L_ + k] = acc * 0.125f;
        }
    }
}

// ---------------------------------------------------------------------------
// K5: softmax stats per row: smax = row max, sinv = 1/sum(exp(x-max)).
// 288 blocks × 256 thr, float4 reads.
// ---------------------------------------------------------------------------
__global__ void kernel_stats(const float* __restrict__ raw,
                             float* __restrict__ smax, float* __restrict__ sinv) {
    int row = blockIdx.x;
    const float4* a = (const float4*)(raw + (size_t)row * L_);
    int t = threadIdx.x;

    float4 v[4];
    float mx = -INFINITY;
#pragma unroll
    for (int i = 0; i < 4; ++i) {
        v[i] = a[t + 256 * i];
        mx = fmaxf(mx, fmaxf(fmaxf(v[i].x, v[i].y), fmaxf(v[i].z, v[i].w)));
    }
    __shared__ float red[256];
    __shared__ float bmax;
    red[t] = mx;
    __syncthreads();
    for (int off = 128; off > 0; off >>= 1) {
        if (t < off) red[t] = fmaxf(red[t], red[t + off]);
        __syncthreads();
    }
    if (t == 0) bmax = red[0];
    __syncthreads();

    float mm = bmax, sum = 0.0f;
#pragma unroll
    for (int i = 0; i < 4; ++i)
        sum += expf(v[i].x - mm) + expf(v[i].y - mm) +
               expf(v[i].z - mm) + expf(v[i].w - mm);
    red[t] = sum;
    __syncthreads();
    for (int off = 128; off > 0; off >>= 1) {
        if (t < off) red[t] += red[t + off];
        __syncthreads();
    }
    if (t == 0) { smax[row] = mm; sinv[row] = 1.0f / red[0]; }
}

// ---------------------------------------------------------------------------
// K6: ctx fused over u + softmax apply + attn write + atomic context scatter.
// One block per (b,h)×256-key chunk. Phase 1: normalize raw -> attn (and LDS).
// Phase 2: float4 V accumulate from LDS attn; reduce; atomicAdd into out.
// ---------------------------------------------------------------------------
__global__ void kernel_ctxf(float* __restrict__ attn, const float* __restrict__ V,
                            const int* __restrict__ Mtop, const float* __restrict__ smax,
                            const float* __restrict__ sinv, float* __restrict__ out) {
    int n = blockIdx.x;
    int x = n & 7, m = n >> 3;
    int chunk = m & (CC_ - 1);
    int bh = (m >> 4) * 8 + x;       // CC_ = 16
    int h = bh & (H_ - 1), b = bh >> 3;
    int k0 = chunk * (L_ / CC_);     // 256 keys
    int t = threadIdx.x;

    __shared__ float sA[U_][256];
    float* abase = attn + (size_t)bh * U_ * L_;
#pragma unroll
    for (int u = 0; u < U_; ++u) {
        int row = bh * U_ + u;
        float e = expf(abase[(size_t)u * L_ + k0 + t] - smax[row]) * sinv[row];
        abase[(size_t)u * L_ + k0 + t] = e;
        sA[u][t] = e;
    }
    __syncthreads();

    int g = t >> 6, lane = t & 63;
    int kl = lane >> 4, d4 = lane & 15;

    float4 acc[U_];
#pragma unroll
    for (int u = 0; u < U_; ++u) acc[u] = make_float4(0.f, 0.f, 0.f, 0.f);

    for (int i = 0; i < 16; ++i) {
        int kloc = (g * 4 + kl) + 16 * i;
        float4 vv = *(const float4*)(V + (size_t)((b * L_ + k0 + kloc) * H_ + h) * D_ + 4 * d4);
#pragma unroll
        for (int u = 0; u < U_; ++u) {
            float av = sA[u][kloc];
            acc[u].x += av * vv.x; acc[u].y += av * vv.y;
            acc[u].z += av * vv.z; acc[u].w += av * vv.w;
        }
    }
#pragma unroll
    for (int u = 0; u < U_; ++u) {
        acc[u].x += __shfl_xor(acc[u].x, 16); acc[u].y += __shfl_xor(acc[u].y, 16);
        acc[u].z += __shfl_xor(acc[u].z, 16); acc[u].w += __shfl_xor(acc[u].w, 16);
        acc[u].x += __shfl_xor(acc[u].x, 32); acc[u].y += __shfl_xor(acc[u].y, 32);
        acc[u].z += __shfl_xor(acc[u].z, 32); acc[u].w += __shfl_xor(acc[u].w, 32);
    }
    __shared__ float4 red[U_][4][16];
    if (kl == 0) {
#pragma unroll
        for (int u = 0; u < U_; ++u) red[u][g][d4] = acc[u];
    }
    __syncthreads();
    if (t < U_ * 16) {
        int u = t >> 4, dd = t & 15;
        float4 s0 = red[u][0][dd], s1 = red[u][1][dd];
        float4 s2 = red[u][2][dd], s3 = red[u][3][dd];
        int lq = Mtop[bh * U_ + u];
        float* o = out + (size_t)((b * L_ + lq) * H_ + h) * D_ + 4 * dd;
        atomicAdd(o + 0, s0.x + s1.x + s2.x + s3.x);
        atomicAdd(o + 1, s0.y + s1.y + s2.y + s3.y);
        atomicAdd(o + 2, s0.z + s1.z + s2.z + s3.z);
        atomicAdd(o + 3, s0.w + s1.w + s2.w + s3.w);
    }
}

extern "C" void kernel_launch(void* const* d_in, const int* in_sizes, int n_in,
                              void* d_out, int out_size, void* d_ws, size_t ws_size,
                              hipStream_t stream) {
    const float* Q   = (const float*)d_in[0];
    const float* K   = (const float*)d_in[1];
    const float* V   = (const float*)d_in[2];
    const int*   idx = (const int*)d_in[3];

    float* ctx_out  = (float*)d_out;                               // B*L*H*D
    float* attn_out = (float*)d_out + (size_t)B_ * L_ * H_ * D_;   // B*H*U*L

    // workspace (floats): dots | vpart | vmean | cand_v | cand_i | Mtop | smax | sinv
    float* dots   = (float*)d_ws;                                   // 32*9*4096 = 1179648
    float* vpart  = dots + (size_t)32 * S_ * L_;                    // 131072
    float* vmean  = vpart + (size_t)B_ * VC_ * H_ * D_;             // 2048
    float* cand_v = vmean + B_ * H_ * D_;                           // 2304
    int*   cand_i = (int*)(cand_v + 32 * TKC_ * U_);                // 2304
    int*   Mtop   = cand_i + 32 * TKC_ * U_;                        // 288
    float* smax   = (float*)(Mtop + 32 * U_);                       // 288
    float* sinv   = smax + 32 * U_;                                 // 288

    kernel_Mv<<<MBLK_ + B_ * VC_, 256, 0, stream>>>(Q, K, idx, dots, V, vpart);
    kernel_topk1<<<B_ * H_ * TKC_, 64, 0, stream>>>(dots, cand_v, cand_i);
    kernel_small<<<64, 64, 0, stream>>>(cand_v, cand_i, Mtop, vpart, vmean);
    kernel_fill_scores<<<FILLBLK_ + 32 * NC_, 256, 0, stream>>>(ctx_out, vmean, Q, K, Mtop, attn_out);
    kernel_stats<<<B_ * H_ * U_, 256, 0, stream>>>(attn_out, smax, sinv);
    kernel_ctxf<<<32 * CC_, 256, 0, stream>>>(attn_out, V, Mtop, smax, sinv, ctx_out);
}